// Round 17
// baseline (128.600 us; speedup 1.0000x reference)
//
#include <hip/hip_runtime.h>

#define S    56
#define SS   3136        // 56*56
#define CD   64
#define C0   128
#define NB   16
#define EPSF 1e-5f
#define L2E  1.44269504088896f

typedef __attribute__((ext_vector_type(8))) short short8;
typedef __attribute__((ext_vector_type(4))) float f32x4;
typedef __attribute__((ext_vector_type(2))) _Float16 h16x2;
typedef unsigned short ushort_t;

__device__ __forceinline__ ushort_t f2bf(float f) {
    unsigned u = __builtin_bit_cast(unsigned, f);
    unsigned r = u + 0x7FFFu + ((u >> 16) & 1u);
    return (ushort_t)(r >> 16);
}
__device__ __forceinline__ unsigned pkrtz_u(float a, float b) {
    return __builtin_bit_cast(unsigned, __builtin_amdgcn_cvt_pkrtz(a, b));
}
__device__ __forceinline__ h16x2 u2h(unsigned u) {
    return __builtin_bit_cast(h16x2, u);
}
__device__ __forceinline__ float fdot2(h16x2 a, h16x2 b, float c) {
#if __has_builtin(__builtin_amdgcn_fdot2)
    return __builtin_amdgcn_fdot2(a, b, c, false);
#else
    return (float)a.x * (float)b.x + (float)a.y * (float)b.y + c;
#endif
}

#if __has_builtin(__builtin_amdgcn_exp2f)
#define EXP2F __builtin_amdgcn_exp2f
#else
#define EXP2F exp2f
#endif

// ---------------------------------------------------------------------------
// MFMA GEMM (conv_down): out[o][m] = BN(sum_c w[o][c]*x[c][m]) (+relu)
// ---------------------------------------------------------------------------
template <int KC, int OC>
__global__ __launch_bounds__(256)
void gemm_mfma(const float* __restrict__ xin, const float* __restrict__ w,
               const float* __restrict__ bn, const float* __restrict__ resid,
               float* __restrict__ out, int relu_in, int relu_out)
{
    constexpr int KSTEPS = KC / 32;
    constexpr int OT     = OC / 64;
    __shared__ char  xT[64 * KC * 2];
    __shared__ float sS[OC], sB[OC];

    int tid = threadIdx.x;
    int n = blockIdx.x / 49, mt = blockIdx.x - (blockIdx.x / 49) * 49;
    int m0 = mt * 64;

    if (tid < OC) {
        float s = bn[tid] * rsqrtf(bn[3 * OC + tid] + EPSF);
        sS[tid] = s;
        sB[tid] = bn[OC + tid] - s * bn[2 * OC + tid];
    }

    int m_l = tid & 63, cq = tid >> 6;
    const float* xb = xin + (size_t)n * KC * SS + m0 + m_l;
    #pragma unroll
    for (int r = 0; r < KSTEPS; ++r) {
        int cbase = cq * 8 + r * 32;
        float v[8];
        #pragma unroll
        for (int u = 0; u < 8; ++u) v[u] = xb[(size_t)(cbase + u) * SS];
        if (relu_in) {
            #pragma unroll
            for (int u = 0; u < 8; ++u) v[u] = fmaxf(v[u], 0.f);
        }
        short8 sv;
        #pragma unroll
        for (int u = 0; u < 8; ++u) ((ushort_t*)&sv)[u] = f2bf(v[u]);
        *(short8*)(xT + m_l * (KC * 2) + ((cbase * 2) ^ ((m_l & 7) << 4))) = sv;
    }
    __syncthreads();

    int wave = tid >> 6, lane = tid & 63;
    int lo = lane & 15, hi = lane >> 4;

    short8 afrag[OT][KSTEPS];
    #pragma unroll
    for (int ot = 0; ot < OT; ++ot) {
        int o = (wave + ot * 4) * 16 + lo;
        #pragma unroll
        for (int ks = 0; ks < KSTEPS; ++ks) {
            const float* wr = w + (size_t)o * KC + ks * 32 + hi * 8;
            short8 a;
            #pragma unroll
            for (int u = 0; u < 8; ++u) ((ushort_t*)&a)[u] = f2bf(wr[u]);
            afrag[ot][ks] = a;
        }
    }

    f32x4 acc[OT][4];
    #pragma unroll
    for (int ot = 0; ot < OT; ++ot)
        #pragma unroll
        for (int ms = 0; ms < 4; ++ms)
            acc[ot][ms] = (f32x4){0.f, 0.f, 0.f, 0.f};

    #pragma unroll
    for (int ms = 0; ms < 4; ++ms) {
        int m_loc = ms * 16 + lo;
        #pragma unroll
        for (int ks = 0; ks < KSTEPS; ++ks) {
            short8 b = *(const short8*)(xT + m_loc * (KC * 2) +
                        (((ks * 32 + hi * 8) * 2) ^ ((m_loc & 7) << 4)));
            #pragma unroll
            for (int ot = 0; ot < OT; ++ot)
                acc[ot][ms] = __builtin_amdgcn_mfma_f32_16x16x32_bf16(
                                  afrag[ot][ks], b, acc[ot][ms], 0, 0, 0);
        }
    }

    #pragma unroll
    for (int ot = 0; ot < OT; ++ot) {
        int o_base = (wave + ot * 4) * 16;
        #pragma unroll
        for (int ms = 0; ms < 4; ++ms) {
            #pragma unroll
            for (int r = 0; r < 4; ++r) {
                int o = o_base + hi * 4 + r;
                int m = m0 + ms * 16 + lo;
                float val = acc[ot][ms][r] * sS[o] + sB[o];
                if (resid) val += resid[((size_t)n * OC + o) * SS + m];
                if (relu_out) val = fmaxf(val, 0.f);
                out[((size_t)n * OC + o) * SS + m] = val;
            }
        }
    }
}

// ---------------------------------------------------------------------------
// qkv GEMM (H direction).  Per-group layouts:
//  qph  [n][m][16w]: word = g*2 + {c01,c23}, q pre-scaled s_qk*L2E
//  kpack[n][m][16w]: word = g*2 + {c01,c23}
//  vpack[n][m/2][64w]: slot = g*8 + c, word = {v(2jp,slot), v(2jp+1,slot)}
// ---------------------------------------------------------------------------
__global__ __launch_bounds__(256)
void qkv_gemm_mfma(const float* __restrict__ xin, const float* __restrict__ w,
                   const float* __restrict__ bn, const float* __restrict__ bnsim,
                   unsigned* __restrict__ qph, unsigned* __restrict__ kpack,
                   unsigned* __restrict__ vpack)
{
    constexpr int KC = 64, OC = 128;
    __shared__ char  xT[64 * KC * 2];
    __shared__ float sS[OC], sB[OC];
    __shared__ float vtile[64][64];
    __shared__ float foldq[8];

    int tid = threadIdx.x;
    int n = blockIdx.x / 49, mt = blockIdx.x - (blockIdx.x / 49) * 49;
    int m0 = mt * 64;

    if (tid < OC) {
        float s = bn[tid] * rsqrtf(bn[3 * OC + tid] + EPSF);
        sS[tid] = s;
        sB[tid] = bn[OC + tid] - s * bn[2 * OC + tid];
    }
    if (tid < 8) foldq[tid] = bnsim[tid] * rsqrtf(bnsim[72 + tid] + EPSF) * L2E;

    int m_l = tid & 63, cq = tid >> 6;
    const float* xb = xin + (size_t)n * KC * SS + m0 + m_l;
    #pragma unroll
    for (int r = 0; r < 2; ++r) {
        int cbase = cq * 8 + r * 32;
        short8 sv;
        #pragma unroll
        for (int u = 0; u < 8; ++u)
            ((ushort_t*)&sv)[u] = f2bf(xb[(size_t)(cbase + u) * SS]);
        *(short8*)(xT + m_l * (KC * 2) + ((cbase * 2) ^ ((m_l & 7) << 4))) = sv;
    }
    __syncthreads();

    int wave = tid >> 6, lane = tid & 63;
    int lo = lane & 15, hi = lane >> 4;

    short8 afrag[2][2];
    #pragma unroll
    for (int ot = 0; ot < 2; ++ot) {
        int o = (wave + ot * 4) * 16 + lo;
        #pragma unroll
        for (int ks = 0; ks < 2; ++ks) {
            const float* wr = w + (size_t)o * KC + ks * 32 + hi * 8;
            short8 a;
            #pragma unroll
            for (int u = 0; u < 8; ++u) ((ushort_t*)&a)[u] = f2bf(wr[u]);
            afrag[ot][ks] = a;
        }
    }

    f32x4 acc[2][4];
    #pragma unroll
    for (int ot = 0; ot < 2; ++ot)
        #pragma unroll
        for (int ms = 0; ms < 4; ++ms)
            acc[ot][ms] = (f32x4){0.f, 0.f, 0.f, 0.f};

    #pragma unroll
    for (int ms = 0; ms < 4; ++ms) {
        int m_loc = ms * 16 + lo;
        #pragma unroll
        for (int ks = 0; ks < 2; ++ks) {
            short8 b = *(const short8*)(xT + m_loc * (KC * 2) +
                        (((ks * 32 + hi * 8) * 2) ^ ((m_loc & 7) << 4)));
            #pragma unroll
            for (int ot = 0; ot < 2; ++ot)
                acc[ot][ms] = __builtin_amdgcn_mfma_f32_16x16x32_bf16(
                                  afrag[ot][ks], b, acc[ot][ms], 0, 0, 0);
        }
    }

    #pragma unroll
    for (int ot = 0; ot < 2; ++ot) {
        int g = wave + ot * 4;
        int o_base = g * 16;
        #pragma unroll
        for (int ms = 0; ms < 4; ++ms) {
            int m_loc = ms * 16 + lo;
            int m = m0 + m_loc;
            float v[4];
            #pragma unroll
            for (int r = 0; r < 4; ++r) {
                int o = o_base + hi * 4 + r;
                v[r] = acc[ot][ms][r] * sS[o] + sB[o];
            }
            if (hi == 0) {
                float fq = foldq[g];
                size_t base = ((size_t)n * SS + m) * 16 + g * 2;
                qph[base]     = pkrtz_u(v[0] * fq, v[1] * fq);
                qph[base + 1] = pkrtz_u(v[2] * fq, v[3] * fq);
            } else if (hi == 1) {
                size_t base = ((size_t)n * SS + m) * 16 + g * 2;
                kpack[base]     = pkrtz_u(v[0], v[1]);
                kpack[base + 1] = pkrtz_u(v[2], v[3]);
            } else {
                int cb = (hi - 2) * 4;
                #pragma unroll
                for (int r = 0; r < 4; ++r)
                    vtile[m_loc][g * 8 + cb + r] = v[r];
            }
        }
    }
    __syncthreads();
    for (int idx = tid; idx < 2048; idx += 256) {
        int jpl = idx >> 6, slot = idx & 63;
        unsigned wv = pkrtz_u(vtile[2 * jpl][slot], vtile[2 * jpl + 1][slot]);
        vpack[((size_t)n * 1568 + (m0 >> 1) + jpl) * 64 + slot] = wv;
    }
}

// ---------------------------------------------------------------------------
// Transpose last two 56x56 dims (float4 global accesses).
// ---------------------------------------------------------------------------
__global__ __launch_bounds__(256)
void transpose_hw(const float* __restrict__ in, float* __restrict__ out)
{
    __shared__ float t[S][57];
    size_t base = (size_t)blockIdx.x * SS;
    for (int idx = threadIdx.x; idx < 784; idx += 256) {
        int a = idx / 14, bq = idx - (idx / 14) * 14;
        float4 v = *(const float4*)&in[base + a * 56 + bq * 4];
        t[a][bq * 4 + 0] = v.x; t[a][bq * 4 + 1] = v.y;
        t[a][bq * 4 + 2] = v.z; t[a][bq * 4 + 3] = v.w;
    }
    __syncthreads();
    for (int idx = threadIdx.x; idx < 784; idx += 256) {
        int b = idx / 14, aq = idx - (idx / 14) * 14;
        float4 r;
        r.x = t[aq * 4 + 0][b]; r.y = t[aq * 4 + 1][b];
        r.z = t[aq * 4 + 2][b]; r.w = t[aq * 4 + 3][b];
        *(float4*)&out[base + b * 56 + aq * 4] = r;
    }
}

// ---------------------------------------------------------------------------
// Fused attention v4: one group per wave, TWO-PASS softmax (scores held as
// packed f16 in 28 VGPRs -> no serial online-softmax chain, no rescale
// branch).  Merged rel rows [112][12w].  LDS 16.1 KB (same as v3).
// MODE 0 (H): attention + epilogue qkv-W GEMM -> oq/ok/ov (f16 pairs).
// MODE 1 (W): V re-paired from ov + epilogue conv_up + resid + ReLU -> dout.
// ---------------------------------------------------------------------------
template <int MODE>
__global__ __launch_bounds__(512)
void attn_fused(const unsigned* __restrict__ qph,
                const unsigned* __restrict__ kpack,
                const unsigned* __restrict__ vin,
                const float* __restrict__ bnsim,   // 4 x 24 (this attn)
                const float* __restrict__ bnout,   // 4 x 128 (this attn)
                const float* __restrict__ rel,     // 16 x 111 (this attn)
                const float* __restrict__ ew,      // epilogue weight [128][64]
                const float* __restrict__ ebn,     // epilogue BN (4 x 128)
                const float* __restrict__ ebnsim,  // MODE0: next bnsim (foldq)
                const float* __restrict__ resid,   // MODE1: x
                unsigned* __restrict__ oq, unsigned* __restrict__ ok,
                unsigned* __restrict__ ov,         // MODE0 out: f16 pairs [n][m][32w]
                float* __restrict__ dout)          // MODE1 output
{
    __shared__ __align__(16) unsigned smem[4032];

    int tid = threadIdx.x;
    int n = blockIdx.x / S, p = blockIdx.x - (blockIdx.x / S) * S;

    // ---- stage K: j-paired klds[jp][g][4] from [n][m][16] (word g*2)
    const unsigned* kp = kpack + ((size_t)n * SS + (size_t)p * S) * 16;
    for (int idx = tid; idx < 224; idx += 512) {
        int jp = idx >> 3, g = idx & 7;
        uint2 a = *(const uint2*)(kp + (2 * jp) * 16 + g * 2);
        uint2 b = *(const uint2*)(kp + (2 * jp + 1) * 16 + g * 2);
        uint4 w; w.x = a.x; w.y = a.y; w.z = b.x; w.w = b.y;
        *(uint4*)&smem[(jp * 8 + g) * 4] = w;
    }
    // ---- stage V (paired f16 words, slot = g*8+c)
    if (MODE == 0) {
        const uint4* vp4 = (const uint4*)(vin +
                           ((size_t)n * 1568 + (size_t)p * 28) * 64);
        for (int idx = tid; idx < 448; idx += 512)
            ((uint4*)(smem + 896))[idx] = vp4[idx];
    } else {
        const unsigned* vt = vin + ((size_t)n * SS + (size_t)p * S) * 32;
        for (int idx = tid; idx < 448; idx += 512) {
            int jp = idx >> 4, q = idx & 15;
            uint2 a = *(const uint2*)(vt + (2 * jp) * 32 + q * 2);
            uint2 b = *(const uint2*)(vt + (2 * jp + 1) * 32 + q * 2);
            uint4 wv;
            wv.x = (a.x & 0xffffu) | (b.x << 16);
            wv.y = (a.x >> 16) | (b.x & 0xffff0000u);
            wv.z = (a.y & 0xffffu) | (b.y << 16);
            wv.w = (a.y >> 16) | (b.y & 0xffff0000u);
            ((uint4*)(smem + 896))[idx] = wv;
        }
    }
    // ---- stage merged rel rows [112][12w]
    for (int d = tid; d < 111; d += 512) {
        smem[2688 + d * 12 + 0] = pkrtz_u(rel[d], rel[111 + d]);
        smem[2688 + d * 12 + 1] = pkrtz_u(rel[222 + d], rel[333 + d]);
        int rd = 110 - d;
        smem[2688 + rd * 12 + 2] = pkrtz_u(rel[444 + d], rel[555 + d]);
        smem[2688 + rd * 12 + 3] = pkrtz_u(rel[666 + d], rel[777 + d]);
    }
    for (int idx = tid; idx < 888; idx += 512) {
        int d = idx >> 3, c = idx & 7;
        float a = rel[(8 + c) * 111 + d];
        float b = d ? rel[(8 + c) * 111 + d - 1] : 0.f;
        smem[2688 + d * 12 + 4 + c] = pkrtz_u(a, b);
    }
    __syncthreads();

    const int g = __builtin_amdgcn_readfirstlane(tid >> 6);
    const int i = tid & 63;
    const int ic = i < S ? i : S - 1;

    float sqk = bnsim[g] * rsqrtf(bnsim[72 + g] + EPSF);
    float sqr = bnsim[8 + g] * rsqrtf(bnsim[80 + g] + EPSF);
    float skr = bnsim[16 + g] * rsqrtf(bnsim[88 + g] + EPSF);
    float bsm = (bnsim[24 + g] - sqk * bnsim[48 + g])
              + (bnsim[32 + g] - sqr * bnsim[56 + g])
              + (bnsim[40 + g] - skr * bnsim[64 + g]);
    float cq = sqr / sqk;
    float ck = skr * L2E;
    float bb = bsm * L2E;

    uint2 qw2 = *(const uint2*)(qph + ((size_t)n * SS + (size_t)p * S + ic) * 16 + g * 2);
    h16x2 qa = u2h(qw2.x), qb = u2h(qw2.y);
    const h16x2 ones = u2h(pkrtz_u(1.f, 1.f));

    // ---- PASS 1: all 56 scores into 28 packed-f16 VGPRs (pure ILP)
    unsigned ps[28];
    #pragma unroll
    for (int jp = 0; jp < 28; ++jp) {
        const int dA = ic - 2 * jp + 55;
        uint4 kq  = *(const uint4*)&smem[(jp * 8 + g) * 4];
        uint4 rqA = *(const uint4*)&smem[2688 + dA * 12];
        uint4 rqB = *(const uint4*)&smem[2688 + (dA - 1) * 12];

        float tq = fdot2(qb, u2h(kq.y), bb); tq = fdot2(qa, u2h(kq.x), tq);
        float tr = fdot2(qb, u2h(rqA.y), 0.f); tr = fdot2(qa, u2h(rqA.x), tr);
        float tk = fdot2(u2h(kq.y), u2h(rqA.w), 0.f);
        tk = fdot2(u2h(kq.x), u2h(rqA.z), tk);
        float pA = fmaf(cq, tr, fmaf(ck, tk, tq));

        tq = fdot2(qb, u2h(kq.w), bb); tq = fdot2(qa, u2h(kq.z), tq);
        tr = fdot2(qb, u2h(rqB.y), 0.f); tr = fdot2(qa, u2h(rqB.x), tr);
        tk = fdot2(u2h(kq.w), u2h(rqB.w), 0.f);
        tk = fdot2(u2h(kq.z), u2h(rqB.z), tk);
        float pB = fmaf(cq, tr, fmaf(ck, tk, tq));

        ps[jp] = pkrtz_u(pA, pB);
    }

    // ---- packed max tree
    h16x2 m2 = u2h(ps[0]);
    #pragma unroll
    for (int jp = 1; jp < 28; ++jp)
        m2 = __builtin_elementwise_max(m2, u2h(ps[jp]));
    float mx = fmaxf((float)m2.x, (float)m2.y);

    // ---- PASS 2: exp + PV accumulate (no serial chain, no branch)
    float Z = 0.f;
    float av[8], ae[8];
    #pragma unroll
    for (int c = 0; c < 8; ++c) { av[c] = 0.f; ae[c] = 0.f; }

    #pragma unroll
    for (int jp = 0; jp < 28; ++jp) {
        const int dA = ic - 2 * jp + 55;
        h16x2 pp = u2h(ps[jp]);
        float eA = EXP2F((float)pp.x - mx);
        float eB = EXP2F((float)pp.y - mx);
        h16x2 ep = u2h(pkrtz_u(eA, eB));
        Z = fdot2(ep, ones, Z);

        const unsigned* vw = &smem[896 + jp * 64 + g * 8];
        uint4 v0 = *(const uint4*)(vw);
        uint4 v1 = *(const uint4*)(vw + 4);
        uint4 r0 = *(const uint4*)&smem[2688 + dA * 12 + 4];
        uint4 r1 = *(const uint4*)&smem[2688 + dA * 12 + 8];

        av[0] = fdot2(ep, u2h(v0.x), av[0]); ae[0] = fdot2(ep, u2h(r0.x), ae[0]);
        av[1] = fdot2(ep, u2h(v0.y), av[1]); ae[1] = fdot2(ep, u2h(r0.y), ae[1]);
        av[2] = fdot2(ep, u2h(v0.z), av[2]); ae[2] = fdot2(ep, u2h(r0.z), ae[2]);
        av[3] = fdot2(ep, u2h(v0.w), av[3]); ae[3] = fdot2(ep, u2h(r0.w), ae[3]);
        av[4] = fdot2(ep, u2h(v1.x), av[4]); ae[4] = fdot2(ep, u2h(r1.x), ae[4]);
        av[5] = fdot2(ep, u2h(v1.y), av[5]); ae[5] = fdot2(ep, u2h(r1.y), ae[5]);
        av[6] = fdot2(ep, u2h(v1.z), av[6]); ae[6] = fdot2(ep, u2h(r1.z), ae[6]);
        av[7] = fdot2(ep, u2h(v1.w), av[7]); ae[7] = fdot2(ep, u2h(r1.w), ae[7]);
    }

    // ---- finalize: BN(out) + pair-sum (registers only)
    float yv[8];
    if (i < S) {
        float inv = 1.f / Z;
        #pragma unroll
        for (int c = 0; c < 8; ++c) {
            int ch = g * 8 + c;
            int oa = ch * 2;
            float se = bnout[oa] * rsqrtf(bnout[384 + oa] + EPSF);
            float be = bnout[128 + oa] - se * bnout[256 + oa];
            float so = bnout[oa + 1] * rsqrtf(bnout[384 + oa + 1] + EPSF);
            float bo = bnout[128 + oa + 1] - so * bnout[256 + oa + 1];
            float y = inv * (se * av[c] + so * ae[c]) + (be + bo);
            if (MODE == 1) y = fmaxf(y, 0.f);
            yv[c] = y;
        }
    }
    __syncthreads();                  // all waves done reading klds/vlds

    // ---- stage 64x56 output tile bf16 [row=i][col=ch], XOR swizzle
    char* tb = (char*)smem;
    if (i < S) {
        short8 w0;
        #pragma unroll
        for (int c = 0; c < 8; ++c) ((ushort_t*)&w0)[c] = f2bf(yv[c]);
        *(short8*)(tb + i * 128 + ((g * 16) ^ ((i & 7) << 4))) = w0;
    }
    __syncthreads();

    // ---- epilogue GEMM: M=128 (o), K=64 (c), N=56 (rows); 8 MFMA/wave
    int lo = i & 15, hi = i >> 4;
    short8 afr[2];
    #pragma unroll
    for (int ks = 0; ks < 2; ++ks) {
        const float* wr = ew + (size_t)(g * 16 + lo) * 64 + ks * 32 + hi * 8;
        short8 a;
        #pragma unroll
        for (int u = 0; u < 8; ++u) ((ushort_t*)&a)[u] = f2bf(wr[u]);
        afr[ks] = a;
    }
    f32x4 acc4[4];
    #pragma unroll
    for (int ms = 0; ms < 4; ++ms) acc4[ms] = (f32x4){0.f, 0.f, 0.f, 0.f};
    #pragma unroll
    for (int ms = 0; ms < 4; ++ms) {
        int row = ms * 16 + lo;
        int sw = (row & 7) << 4;
        #pragma unroll
        for (int ks = 0; ks < 2; ++ks) {
            short8 b = *(const short8*)(tb + row * 128 + ((ks * 64 + hi * 16) ^ sw));
            acc4[ms] = __builtin_amdgcn_mfma_f32_16x16x32_bf16(afr[ks], b, acc4[ms], 0, 0, 0);
        }
    }

    float sSv[4], sBv[4];
    #pragma unroll
    for (int r = 0; r < 4; ++r) {
        int o = g * 16 + hi * 4 + r;
        float s = ebn[o] * rsqrtf(ebn[384 + o] + EPSF);
        sSv[r] = s;
        sBv[r] = ebn[128 + o] - s * ebn[256 + o];
    }

    if (MODE == 0) {
        float fq = ebnsim[g] * rsqrtf(ebnsim[72 + g] + EPSF) * L2E;
        #pragma unroll
        for (int ms = 0; ms < 4; ++ms) {
            int mrow = ms * 16 + lo;
            if (mrow < S) {
                size_t mW = (size_t)mrow * S + p;
                float v0 = acc4[ms][0] * sSv[0] + sBv[0];
                float v1 = acc4[ms][1] * sSv[1] + sBv[1];
                float v2 = acc4[ms][2] * sSv[2] + sBv[2];
                float v3 = acc4[ms][3] * sSv[3] + sBv[3];
                if (hi == 0) {
                    size_t base = ((size_t)n * SS + mW) * 16 + g * 2;
                    oq[base]     = pkrtz_u(v0 * fq, v1 * fq);
                    oq[base + 1] = pkrtz_u(v2 * fq, v3 * fq);
                } else if (hi == 1) {
                    size_t base = ((size_t)n * SS + mW) * 16 + g * 2;
                    ok[base]     = pkrtz_u(v0, v1);
                    ok[base + 1] = pkrtz_u(v2, v3);
                } else {
                    size_t basev = ((size_t)n * SS + mW) * 32 + g * 4 + (hi - 2) * 2;
                    ov[basev]     = pkrtz_u(v0, v1);
                    ov[basev + 1] = pkrtz_u(v2, v3);
                }
            }
        }
    } else {
        #pragma unroll
        for (int ms = 0; ms < 4; ++ms) {
            int mrow = ms * 16 + lo;
            if (mrow < S) {
                #pragma unroll
                for (int r = 0; r < 4; ++r) {
                    int o = g * 16 + hi * 4 + r;
                    size_t oi = ((size_t)n * C0 + o) * SS + (size_t)p * S + mrow;
                    float val = acc4[ms][r] * sSv[r] + sBv[r] + resid[oi];
                    dout[oi] = fmaxf(val, 0.f);
                }
            }
        }
    }
}

extern "C" void kernel_launch(void* const* d_in, const int* in_sizes, int n_in,
                              void* d_out, int out_size, void* d_ws, size_t ws_size,
                              hipStream_t stream)
{
    const float* x      = (const float*)d_in[0];
    const float* cdw    = (const float*)d_in[1];
    const float* bn1    = (const float*)d_in[2];
    const float* hqkv   = (const float*)d_in[3];
    const float* hbnqkv = (const float*)d_in[4];
    const float* hbnsim = (const float*)d_in[5];
    const float* hbnout = (const float*)d_in[6];
    const float* hrel   = (const float*)d_in[7];
    const float* wqkv   = (const float*)d_in[8];
    const float* wbnqkv = (const float*)d_in[9];
    const float* wbnsim = (const float*)d_in[10];
    const float* wbnout = (const float*)d_in[11];
    const float* wrel   = (const float*)d_in[12];
    const float* cuw    = (const float*)d_in[13];
    const float* bn2    = (const float*)d_in[14];

    float*    bufA   = (float*)d_ws;                            // conv_down out
    float*    bufB   = bufA + (size_t)NB * CD * SS;             // transposed
    unsigned* qph    = (unsigned*)(bufB + (size_t)NB * CD * SS);
    unsigned* kpack  = qph + (size_t)NB * SS * 16;
    unsigned* vpack  = kpack + (size_t)NB * SS * 16;            // NB*1568*64 w
    unsigned* qph2   = vpack + (size_t)NB * 1568 * 64;
    unsigned* kpack2 = qph2 + (size_t)NB * SS * 16;
    unsigned* ovbuf  = kpack2 + (size_t)NB * SS * 16;           // NB*SS*32 w

    // 1. conv_down + BN + ReLU -> bufA [b,c,(h,w)]
    gemm_mfma<128, 64><<<NB * 49, 256, 0, stream>>>(x, cdw, bn1, nullptr, bufA, 0, 1);
    // 2. transpose -> bufB [b,c,(w,h)]
    transpose_hw<<<NB * CD, 256, 0, stream>>>(bufA, bufB);
    // 3. qkv GEMM (H) -> qph, kpack, vpack
    qkv_gemm_mfma<<<NB * 49, 256, 0, stream>>>(bufB, hqkv, hbnqkv, hbnsim, qph, kpack, vpack);
    // 4. attn H + fused qkv-W GEMM -> qph2, kpack2, ovbuf
    attn_fused<0><<<NB * S, 512, 0, stream>>>(qph, kpack, vpack,
        hbnsim, hbnout, hrel, wqkv, wbnqkv, wbnsim, nullptr,
        qph2, kpack2, ovbuf, nullptr);
    // 5. attn W + fused conv_up + BN + resid + ReLU -> d_out
    attn_fused<1><<<NB * S, 512, 0, stream>>>(qph2, kpack2, ovbuf,
        wbnsim, wbnout, wrel, cuw, bn2, nullptr, x,
        nullptr, nullptr, nullptr, (float*)d_out);
}

// Round 18
// 102.961 us; speedup vs baseline: 1.2490x; 1.2490x over previous
//
#include <hip/hip_runtime.h>

#define S    56
#define SS   3136        // 56*56
#define CD   64
#define C0   128
#define NB   16
#define EPSF 1e-5f
#define L2E  1.44269504088896f

typedef __attribute__((ext_vector_type(8))) short short8;
typedef __attribute__((ext_vector_type(4))) float f32x4;
typedef __attribute__((ext_vector_type(2))) _Float16 h16x2;
typedef unsigned short ushort_t;

__device__ __forceinline__ ushort_t f2bf(float f) {
    unsigned u = __builtin_bit_cast(unsigned, f);
    unsigned r = u + 0x7FFFu + ((u >> 16) & 1u);
    return (ushort_t)(r >> 16);
}
__device__ __forceinline__ unsigned pkrtz_u(float a, float b) {
    return __builtin_bit_cast(unsigned, __builtin_amdgcn_cvt_pkrtz(a, b));
}
__device__ __forceinline__ h16x2 u2h(unsigned u) {
    return __builtin_bit_cast(h16x2, u);
}
__device__ __forceinline__ float fdot2(h16x2 a, h16x2 b, float c) {
#if __has_builtin(__builtin_amdgcn_fdot2)
    return __builtin_amdgcn_fdot2(a, b, c, false);
#else
    return (float)a.x * (float)b.x + (float)a.y * (float)b.y + c;
#endif
}

#if __has_builtin(__builtin_amdgcn_exp2f)
#define EXP2F __builtin_amdgcn_exp2f
#else
#define EXP2F exp2f
#endif

// ---------------------------------------------------------------------------
// MFMA GEMM (conv_down): out[o][m] = BN(sum_c w[o][c]*x[c][m]) (+relu)
// ---------------------------------------------------------------------------
template <int KC, int OC>
__global__ __launch_bounds__(256)
void gemm_mfma(const float* __restrict__ xin, const float* __restrict__ w,
               const float* __restrict__ bn, const float* __restrict__ resid,
               float* __restrict__ out, int relu_in, int relu_out)
{
    constexpr int KSTEPS = KC / 32;
    constexpr int OT     = OC / 64;
    __shared__ char  xT[64 * KC * 2];
    __shared__ float sS[OC], sB[OC];

    int tid = threadIdx.x;
    int n = blockIdx.x / 49, mt = blockIdx.x - (blockIdx.x / 49) * 49;
    int m0 = mt * 64;

    if (tid < OC) {
        float s = bn[tid] * rsqrtf(bn[3 * OC + tid] + EPSF);
        sS[tid] = s;
        sB[tid] = bn[OC + tid] - s * bn[2 * OC + tid];
    }

    int m_l = tid & 63, cq = tid >> 6;
    const float* xb = xin + (size_t)n * KC * SS + m0 + m_l;
    #pragma unroll
    for (int r = 0; r < KSTEPS; ++r) {
        int cbase = cq * 8 + r * 32;
        float v[8];
        #pragma unroll
        for (int u = 0; u < 8; ++u) v[u] = xb[(size_t)(cbase + u) * SS];
        if (relu_in) {
            #pragma unroll
            for (int u = 0; u < 8; ++u) v[u] = fmaxf(v[u], 0.f);
        }
        short8 sv;
        #pragma unroll
        for (int u = 0; u < 8; ++u) ((ushort_t*)&sv)[u] = f2bf(v[u]);
        *(short8*)(xT + m_l * (KC * 2) + ((cbase * 2) ^ ((m_l & 7) << 4))) = sv;
    }
    __syncthreads();

    int wave = tid >> 6, lane = tid & 63;
    int lo = lane & 15, hi = lane >> 4;

    short8 afrag[OT][KSTEPS];
    #pragma unroll
    for (int ot = 0; ot < OT; ++ot) {
        int o = (wave + ot * 4) * 16 + lo;
        #pragma unroll
        for (int ks = 0; ks < KSTEPS; ++ks) {
            const float* wr = w + (size_t)o * KC + ks * 32 + hi * 8;
            short8 a;
            #pragma unroll
            for (int u = 0; u < 8; ++u) ((ushort_t*)&a)[u] = f2bf(wr[u]);
            afrag[ot][ks] = a;
        }
    }

    f32x4 acc[OT][4];
    #pragma unroll
    for (int ot = 0; ot < OT; ++ot)
        #pragma unroll
        for (int ms = 0; ms < 4; ++ms)
            acc[ot][ms] = (f32x4){0.f, 0.f, 0.f, 0.f};

    #pragma unroll
    for (int ms = 0; ms < 4; ++ms) {
        int m_loc = ms * 16 + lo;
        #pragma unroll
        for (int ks = 0; ks < KSTEPS; ++ks) {
            short8 b = *(const short8*)(xT + m_loc * (KC * 2) +
                        (((ks * 32 + hi * 8) * 2) ^ ((m_loc & 7) << 4)));
            #pragma unroll
            for (int ot = 0; ot < OT; ++ot)
                acc[ot][ms] = __builtin_amdgcn_mfma_f32_16x16x32_bf16(
                                  afrag[ot][ks], b, acc[ot][ms], 0, 0, 0);
        }
    }

    #pragma unroll
    for (int ot = 0; ot < OT; ++ot) {
        int o_base = (wave + ot * 4) * 16;
        #pragma unroll
        for (int ms = 0; ms < 4; ++ms) {
            #pragma unroll
            for (int r = 0; r < 4; ++r) {
                int o = o_base + hi * 4 + r;
                int m = m0 + ms * 16 + lo;
                float val = acc[ot][ms][r] * sS[o] + sB[o];
                if (resid) val += resid[((size_t)n * OC + o) * SS + m];
                if (relu_out) val = fmaxf(val, 0.f);
                out[((size_t)n * OC + o) * SS + m] = val;
            }
        }
    }
}

// ---------------------------------------------------------------------------
// qkv GEMM (H direction).  Per-group layouts:
//  qph  [n][m][16w]: word = g*2 + {c01,c23}, q pre-scaled s_qk*L2E
//  kpack[n][m][16w]: word = g*2 + {c01,c23}
//  vpack[n][m/2][64w]: slot = g*8 + c, word = {v(2jp,slot), v(2jp+1,slot)}
// ---------------------------------------------------------------------------
__global__ __launch_bounds__(256)
void qkv_gemm_mfma(const float* __restrict__ xin, const float* __restrict__ w,
                   const float* __restrict__ bn, const float* __restrict__ bnsim,
                   unsigned* __restrict__ qph, unsigned* __restrict__ kpack,
                   unsigned* __restrict__ vpack)
{
    constexpr int KC = 64, OC = 128;
    __shared__ char  xT[64 * KC * 2];
    __shared__ float sS[OC], sB[OC];
    __shared__ float vtile[64][64];
    __shared__ float foldq[8];

    int tid = threadIdx.x;
    int n = blockIdx.x / 49, mt = blockIdx.x - (blockIdx.x / 49) * 49;
    int m0 = mt * 64;

    if (tid < OC) {
        float s = bn[tid] * rsqrtf(bn[3 * OC + tid] + EPSF);
        sS[tid] = s;
        sB[tid] = bn[OC + tid] - s * bn[2 * OC + tid];
    }
    if (tid < 8) foldq[tid] = bnsim[tid] * rsqrtf(bnsim[72 + tid] + EPSF) * L2E;

    int m_l = tid & 63, cq = tid >> 6;
    const float* xb = xin + (size_t)n * KC * SS + m0 + m_l;
    #pragma unroll
    for (int r = 0; r < 2; ++r) {
        int cbase = cq * 8 + r * 32;
        short8 sv;
        #pragma unroll
        for (int u = 0; u < 8; ++u)
            ((ushort_t*)&sv)[u] = f2bf(xb[(size_t)(cbase + u) * SS]);
        *(short8*)(xT + m_l * (KC * 2) + ((cbase * 2) ^ ((m_l & 7) << 4))) = sv;
    }
    __syncthreads();

    int wave = tid >> 6, lane = tid & 63;
    int lo = lane & 15, hi = lane >> 4;

    short8 afrag[2][2];
    #pragma unroll
    for (int ot = 0; ot < 2; ++ot) {
        int o = (wave + ot * 4) * 16 + lo;
        #pragma unroll
        for (int ks = 0; ks < 2; ++ks) {
            const float* wr = w + (size_t)o * KC + ks * 32 + hi * 8;
            short8 a;
            #pragma unroll
            for (int u = 0; u < 8; ++u) ((ushort_t*)&a)[u] = f2bf(wr[u]);
            afrag[ot][ks] = a;
        }
    }

    f32x4 acc[2][4];
    #pragma unroll
    for (int ot = 0; ot < 2; ++ot)
        #pragma unroll
        for (int ms = 0; ms < 4; ++ms)
            acc[ot][ms] = (f32x4){0.f, 0.f, 0.f, 0.f};

    #pragma unroll
    for (int ms = 0; ms < 4; ++ms) {
        int m_loc = ms * 16 + lo;
        #pragma unroll
        for (int ks = 0; ks < 2; ++ks) {
            short8 b = *(const short8*)(xT + m_loc * (KC * 2) +
                        (((ks * 32 + hi * 8) * 2) ^ ((m_loc & 7) << 4)));
            #pragma unroll
            for (int ot = 0; ot < 2; ++ot)
                acc[ot][ms] = __builtin_amdgcn_mfma_f32_16x16x32_bf16(
                                  afrag[ot][ks], b, acc[ot][ms], 0, 0, 0);
        }
    }

    #pragma unroll
    for (int ot = 0; ot < 2; ++ot) {
        int g = wave + ot * 4;
        int o_base = g * 16;
        #pragma unroll
        for (int ms = 0; ms < 4; ++ms) {
            int m_loc = ms * 16 + lo;
            int m = m0 + m_loc;
            float v[4];
            #pragma unroll
            for (int r = 0; r < 4; ++r) {
                int o = o_base + hi * 4 + r;
                v[r] = acc[ot][ms][r] * sS[o] + sB[o];
            }
            if (hi == 0) {
                float fq = foldq[g];
                size_t base = ((size_t)n * SS + m) * 16 + g * 2;
                qph[base]     = pkrtz_u(v[0] * fq, v[1] * fq);
                qph[base + 1] = pkrtz_u(v[2] * fq, v[3] * fq);
            } else if (hi == 1) {
                size_t base = ((size_t)n * SS + m) * 16 + g * 2;
                kpack[base]     = pkrtz_u(v[0], v[1]);
                kpack[base + 1] = pkrtz_u(v[2], v[3]);
            } else {
                int cb = (hi - 2) * 4;
                #pragma unroll
                for (int r = 0; r < 4; ++r)
                    vtile[m_loc][g * 8 + cb + r] = v[r];
            }
        }
    }
    __syncthreads();
    for (int idx = tid; idx < 2048; idx += 256) {
        int jpl = idx >> 6, slot = idx & 63;
        unsigned wv = pkrtz_u(vtile[2 * jpl][slot], vtile[2 * jpl + 1][slot]);
        vpack[((size_t)n * 1568 + (m0 >> 1) + jpl) * 64 + slot] = wv;
    }
}

// ---------------------------------------------------------------------------
// Transpose last two 56x56 dims (float4 global accesses).
// ---------------------------------------------------------------------------
__global__ __launch_bounds__(256)
void transpose_hw(const float* __restrict__ in, float* __restrict__ out)
{
    __shared__ float t[S][57];
    size_t base = (size_t)blockIdx.x * SS;
    for (int idx = threadIdx.x; idx < 784; idx += 256) {
        int a = idx / 14, bq = idx - (idx / 14) * 14;
        float4 v = *(const float4*)&in[base + a * 56 + bq * 4];
        t[a][bq * 4 + 0] = v.x; t[a][bq * 4 + 1] = v.y;
        t[a][bq * 4 + 2] = v.z; t[a][bq * 4 + 3] = v.w;
    }
    __syncthreads();
    for (int idx = threadIdx.x; idx < 784; idx += 256) {
        int b = idx / 14, aq = idx - (idx / 14) * 14;
        float4 r;
        r.x = t[aq * 4 + 0][b]; r.y = t[aq * 4 + 1][b];
        r.z = t[aq * 4 + 2][b]; r.w = t[aq * 4 + 3][b];
        *(float4*)&out[base + b * 56 + aq * 4] = r;
    }
}

// ---------------------------------------------------------------------------
// Fused attention v3b (R16 + unroll-4 jp loop): one group per wave, online
// softmax, merged rel rows [112][12w], f16 ov.  LDS 16.1 KB.
// MODE 0 (H): attention + epilogue qkv-W GEMM -> oq/ok/ov (f16 pairs).
// MODE 1 (W): V re-paired from ov + epilogue conv_up + resid + ReLU -> dout.
// ---------------------------------------------------------------------------
template <int MODE>
__global__ __launch_bounds__(512)
void attn_fused(const unsigned* __restrict__ qph,
                const unsigned* __restrict__ kpack,
                const unsigned* __restrict__ vin,
                const float* __restrict__ bnsim,   // 4 x 24 (this attn)
                const float* __restrict__ bnout,   // 4 x 128 (this attn)
                const float* __restrict__ rel,     // 16 x 111 (this attn)
                const float* __restrict__ ew,      // epilogue weight [128][64]
                const float* __restrict__ ebn,     // epilogue BN (4 x 128)
                const float* __restrict__ ebnsim,  // MODE0: next bnsim (foldq)
                const float* __restrict__ resid,   // MODE1: x
                unsigned* __restrict__ oq, unsigned* __restrict__ ok,
                unsigned* __restrict__ ov,         // MODE0 out: f16 pairs [n][m][32w]
                float* __restrict__ dout)          // MODE1 output
{
    __shared__ __align__(16) unsigned smem[4032];

    int tid = threadIdx.x;
    int n = blockIdx.x / S, p = blockIdx.x - (blockIdx.x / S) * S;

    // ---- stage K: j-paired klds[jp][g][4] from [n][m][16] (word g*2)
    const unsigned* kp = kpack + ((size_t)n * SS + (size_t)p * S) * 16;
    for (int idx = tid; idx < 224; idx += 512) {
        int jp = idx >> 3, g = idx & 7;
        uint2 a = *(const uint2*)(kp + (2 * jp) * 16 + g * 2);
        uint2 b = *(const uint2*)(kp + (2 * jp + 1) * 16 + g * 2);
        uint4 w; w.x = a.x; w.y = a.y; w.z = b.x; w.w = b.y;
        *(uint4*)&smem[(jp * 8 + g) * 4] = w;
    }
    // ---- stage V (paired f16 words, slot = g*8+c)
    if (MODE == 0) {
        const uint4* vp4 = (const uint4*)(vin +
                           ((size_t)n * 1568 + (size_t)p * 28) * 64);
        for (int idx = tid; idx < 448; idx += 512)
            ((uint4*)(smem + 896))[idx] = vp4[idx];
    } else {
        const unsigned* vt = vin + ((size_t)n * SS + (size_t)p * S) * 32;
        for (int idx = tid; idx < 448; idx += 512) {
            int jp = idx >> 4, q = idx & 15;
            uint2 a = *(const uint2*)(vt + (2 * jp) * 32 + q * 2);
            uint2 b = *(const uint2*)(vt + (2 * jp + 1) * 32 + q * 2);
            uint4 wv;
            wv.x = (a.x & 0xffffu) | (b.x << 16);
            wv.y = (a.x >> 16) | (b.x & 0xffff0000u);
            wv.z = (a.y & 0xffffu) | (b.y << 16);
            wv.w = (a.y >> 16) | (b.y & 0xffff0000u);
            ((uint4*)(smem + 896))[idx] = wv;
        }
    }
    // ---- stage merged rel rows [112][12w]
    for (int d = tid; d < 111; d += 512) {
        smem[2688 + d * 12 + 0] = pkrtz_u(rel[d], rel[111 + d]);
        smem[2688 + d * 12 + 1] = pkrtz_u(rel[222 + d], rel[333 + d]);
        int rd = 110 - d;
        smem[2688 + rd * 12 + 2] = pkrtz_u(rel[444 + d], rel[555 + d]);
        smem[2688 + rd * 12 + 3] = pkrtz_u(rel[666 + d], rel[777 + d]);
    }
    for (int idx = tid; idx < 888; idx += 512) {
        int d = idx >> 3, c = idx & 7;
        float a = rel[(8 + c) * 111 + d];
        float b = d ? rel[(8 + c) * 111 + d - 1] : 0.f;
        smem[2688 + d * 12 + 4 + c] = pkrtz_u(a, b);
    }
    __syncthreads();

    const int g = __builtin_amdgcn_readfirstlane(tid >> 6);
    const int i = tid & 63;
    const int ic = i < S ? i : S - 1;

    float sqk = bnsim[g] * rsqrtf(bnsim[72 + g] + EPSF);
    float sqr = bnsim[8 + g] * rsqrtf(bnsim[80 + g] + EPSF);
    float skr = bnsim[16 + g] * rsqrtf(bnsim[88 + g] + EPSF);
    float bsm = (bnsim[24 + g] - sqk * bnsim[48 + g])
              + (bnsim[32 + g] - sqr * bnsim[56 + g])
              + (bnsim[40 + g] - skr * bnsim[64 + g]);
    float cq = sqr / sqk;
    float ck = skr * L2E;
    float bb = bsm * L2E;

    uint2 qw2 = *(const uint2*)(qph + ((size_t)n * SS + (size_t)p * S + ic) * 16 + g * 2);
    h16x2 qa = u2h(qw2.x), qb = u2h(qw2.y);
    const h16x2 ones = u2h(pkrtz_u(1.f, 1.f));

    float mr = -3e38f, Z = 0.f;
    float av[8], ae[8];
    #pragma unroll
    for (int c = 0; c < 8; ++c) { av[c] = 0.f; ae[c] = 0.f; }

    #pragma unroll 4
    for (int jp = 0; jp < 28; ++jp) {
        const int dA = ic - 2 * jp + 55;
        uint4 kq  = *(const uint4*)&smem[(jp * 8 + g) * 4];
        uint4 rqA = *(const uint4*)&smem[2688 + dA * 12];
        uint4 rqB = *(const uint4*)&smem[2688 + (dA - 1) * 12];

        float tq = fdot2(qb, u2h(kq.y), bb); tq = fdot2(qa, u2h(kq.x), tq);
        float tr = fdot2(qb, u2h(rqA.y), 0.f); tr = fdot2(qa, u2h(rqA.x), tr);
        float tk = fdot2(u2h(kq.y), u2h(rqA.w), 0.f);
        tk = fdot2(u2h(kq.x), u2h(rqA.z), tk);
        float pA = fmaf(cq, tr, fmaf(ck, tk, tq));

        tq = fdot2(qb, u2h(kq.w), bb); tq = fdot2(qa, u2h(kq.z), tq);
        tr = fdot2(qb, u2h(rqB.y), 0.f); tr = fdot2(qa, u2h(rqB.x), tr);
        tk = fdot2(u2h(kq.w), u2h(rqB.w), 0.f);
        tk = fdot2(u2h(kq.z), u2h(rqB.z), tk);
        float pB = fmaf(cq, tr, fmaf(ck, tk, tq));

        float nm = fmaxf(mr, fmaxf(pA, pB));
        if (!__all(nm - mr <= 12.0f)) {
            float s = EXP2F(mr - nm);
            mr = nm; Z *= s;
            #pragma unroll
            for (int c = 0; c < 8; ++c) { av[c] *= s; ae[c] *= s; }
        }
        float eA = EXP2F(pA - mr), eB = EXP2F(pB - mr);
        h16x2 ep = u2h(pkrtz_u(eA, eB));
        Z = fdot2(ep, ones, Z);

        const unsigned* vw = &smem[896 + jp * 64 + g * 8];
        uint4 v0 = *(const uint4*)(vw);
        uint4 v1 = *(const uint4*)(vw + 4);
        uint4 r0 = *(const uint4*)&smem[2688 + dA * 12 + 4];
        uint4 r1 = *(const uint4*)&smem[2688 + dA * 12 + 8];

        av[0] = fdot2(ep, u2h(v0.x), av[0]); ae[0] = fdot2(ep, u2h(r0.x), ae[0]);
        av[1] = fdot2(ep, u2h(v0.y), av[1]); ae[1] = fdot2(ep, u2h(r0.y), ae[1]);
        av[2] = fdot2(ep, u2h(v0.z), av[2]); ae[2] = fdot2(ep, u2h(r0.z), ae[2]);
        av[3] = fdot2(ep, u2h(v0.w), av[3]); ae[3] = fdot2(ep, u2h(r0.w), ae[3]);
        av[4] = fdot2(ep, u2h(v1.x), av[4]); ae[4] = fdot2(ep, u2h(r1.x), ae[4]);
        av[5] = fdot2(ep, u2h(v1.y), av[5]); ae[5] = fdot2(ep, u2h(r1.y), ae[5]);
        av[6] = fdot2(ep, u2h(v1.z), av[6]); ae[6] = fdot2(ep, u2h(r1.z), ae[6]);
        av[7] = fdot2(ep, u2h(v1.w), av[7]); ae[7] = fdot2(ep, u2h(r1.w), ae[7]);
    }

    // ---- finalize: BN(out) + pair-sum (registers only)
    float yv[8];
    if (i < S) {
        float inv = 1.f / Z;
        #pragma unroll
        for (int c = 0; c < 8; ++c) {
            int ch = g * 8 + c;
            int oa = ch * 2;
            float se = bnout[oa] * rsqrtf(bnout[384 + oa] + EPSF);
            float be = bnout[128 + oa] - se * bnout[256 + oa];
            float so = bnout[oa + 1] * rsqrtf(bnout[384 + oa + 1] + EPSF);
            float bo = bnout[128 + oa + 1] - so * bnout[256 + oa + 1];
            float y = inv * (se * av[c] + so * ae[c]) + (be + bo);
            if (MODE == 1) y = fmaxf(y, 0.f);
            yv[c] = y;
        }
    }
    __syncthreads();                  // all waves done reading klds/vlds

    // ---- stage 64x56 output tile bf16 [row=i][col=ch], XOR swizzle
    char* tb = (char*)smem;
    if (i < S) {
        short8 w0;
        #pragma unroll
        for (int c = 0; c < 8; ++c) ((ushort_t*)&w0)[c] = f2bf(yv[c]);
        *(short8*)(tb + i * 128 + ((g * 16) ^ ((i & 7) << 4))) = w0;
    }
    __syncthreads();

    // ---- epilogue GEMM: M=128 (o), K=64 (c), N=56 (rows); 8 MFMA/wave
    int lo = i & 15, hi = i >> 4;
    short8 afr[2];
    #pragma unroll
    for (int ks = 0; ks < 2; ++ks) {
        const float* wr = ew + (size_t)(g * 16 + lo) * 64 + ks * 32 + hi * 8;
        short8 a;
        #pragma unroll
        for (int u = 0; u < 8; ++u) ((ushort_t*)&a)[u] = f2bf(wr[u]);
        afr[ks] = a;
    }
    f32x4 acc4[4];
    #pragma unroll
    for (int ms = 0; ms < 4; ++ms) acc4[ms] = (f32x4){0.f, 0.f, 0.f, 0.f};
    #pragma unroll
    for (int ms = 0; ms < 4; ++ms) {
        int row = ms * 16 + lo;
        int sw = (row & 7) << 4;
        #pragma unroll
        for (int ks = 0; ks < 2; ++ks) {
            short8 b = *(const short8*)(tb + row * 128 + ((ks * 64 + hi * 16) ^ sw));
            acc4[ms] = __builtin_amdgcn_mfma_f32_16x16x32_bf16(afr[ks], b, acc4[ms], 0, 0, 0);
        }
    }

    float sSv[4], sBv[4];
    #pragma unroll
    for (int r = 0; r < 4; ++r) {
        int o = g * 16 + hi * 4 + r;
        float s = ebn[o] * rsqrtf(ebn[384 + o] + EPSF);
        sSv[r] = s;
        sBv[r] = ebn[128 + o] - s * ebn[256 + o];
    }

    if (MODE == 0) {
        float fq = ebnsim[g] * rsqrtf(ebnsim[72 + g] + EPSF) * L2E;
        #pragma unroll
        for (int ms = 0; ms < 4; ++ms) {
            int mrow = ms * 16 + lo;
            if (mrow < S) {
                size_t mW = (size_t)mrow * S + p;
                float v0 = acc4[ms][0] * sSv[0] + sBv[0];
                float v1 = acc4[ms][1] * sSv[1] + sBv[1];
                float v2 = acc4[ms][2] * sSv[2] + sBv[2];
                float v3 = acc4[ms][3] * sSv[3] + sBv[3];
                if (hi == 0) {
                    size_t base = ((size_t)n * SS + mW) * 16 + g * 2;
                    oq[base]     = pkrtz_u(v0 * fq, v1 * fq);
                    oq[base + 1] = pkrtz_u(v2 * fq, v3 * fq);
                } else if (hi == 1) {
                    size_t base = ((size_t)n * SS + mW) * 16 + g * 2;
                    ok[base]     = pkrtz_u(v0, v1);
                    ok[base + 1] = pkrtz_u(v2, v3);
                } else {
                    size_t basev = ((size_t)n * SS + mW) * 32 + g * 4 + (hi - 2) * 2;
                    ov[basev]     = pkrtz_u(v0, v1);
                    ov[basev + 1] = pkrtz_u(v2, v3);
                }
            }
        }
    } else {
        #pragma unroll
        for (int ms = 0; ms < 4; ++ms) {
            int mrow = ms * 16 + lo;
            if (mrow < S) {
                #pragma unroll
                for (int r = 0; r < 4; ++r) {
                    int o = g * 16 + hi * 4 + r;
                    size_t oi = ((size_t)n * C0 + o) * SS + (size_t)p * S + mrow;
                    float val = acc4[ms][r] * sSv[r] + sBv[r] + resid[oi];
                    dout[oi] = fmaxf(val, 0.f);
                }
            }
        }
    }
}

extern "C" void kernel_launch(void* const* d_in, const int* in_sizes, int n_in,
                              void* d_out, int out_size, void* d_ws, size_t ws_size,
                              hipStream_t stream)
{
    const float* x      = (const float*)d_in[0];
    const float* cdw    = (const float*)d_in[1];
    const float* bn1    = (const float*)d_in[2];
    const float* hqkv   = (const float*)d_in[3];
    const float* hbnqkv = (const float*)d_in[4];
    const float* hbnsim = (const float*)d_in[5];
    const float* hbnout = (const float*)d_in[6];
    const float* hrel   = (const float*)d_in[7];
    const float* wqkv   = (const float*)d_in[8];
    const float* wbnqkv = (const float*)d_in[9];
    const float* wbnsim = (const float*)d_in[10];
    const float* wbnout = (const float*)d_in[11];
    const float* wrel   = (const float*)d_in[12];
    const float* cuw    = (const float*)d_in[13];
    const float* bn2    = (const float*)d_in[14];

    float*    bufA   = (float*)d_ws;                            // conv_down out
    float*    bufB   = bufA + (size_t)NB * CD * SS;             // transposed
    unsigned* qph    = (unsigned*)(bufB + (size_t)NB * CD * SS);
    unsigned* kpack  = qph + (size_t)NB * SS * 16;
    unsigned* vpack  = kpack + (size_t)NB * SS * 16;            // NB*1568*64 w
    unsigned* qph2   = vpack + (size_t)NB * 1568 * 64;
    unsigned* kpack2 = qph2 + (size_t)NB * SS * 16;
    unsigned* ovbuf  = kpack2 + (size_t)NB * SS * 16;           // NB*SS*32 w

    // 1. conv_down + BN + ReLU -> bufA [b,c,(h,w)]
    gemm_mfma<128, 64><<<NB * 49, 256, 0, stream>>>(x, cdw, bn1, nullptr, bufA, 0, 1);
    // 2. transpose -> bufB [b,c,(w,h)]
    transpose_hw<<<NB * CD, 256, 0, stream>>>(bufA, bufB);
    // 3. qkv GEMM (H) -> qph, kpack, vpack
    qkv_gemm_mfma<<<NB * 49, 256, 0, stream>>>(bufB, hqkv, hbnqkv, hbnsim, qph, kpack, vpack);
    // 4. attn H + fused qkv-W GEMM -> qph2, kpack2, ovbuf
    attn_fused<0><<<NB * S, 512, 0, stream>>>(qph, kpack, vpack,
        hbnsim, hbnout, hrel, wqkv, wbnqkv, wbnsim, nullptr,
        qph2, kpack2, ovbuf, nullptr);
    // 5. attn W + fused conv_up + BN + resid + ReLU -> d_out
    attn_fused<1><<<NB * S, 512, 0, stream>>>(qph2, kpack2, ovbuf,
        wbnsim, wbnout, wrel, cuw, bn2, nullptr, x,
        nullptr, nullptr, nullptr, (float*)d_out);
}